// Round 20
// baseline (927.194 us; speedup 1.0000x reference)
//
#include <hip/hip_runtime.h>

// TruncatedHistoryAttn, round 26 = round 23 VERBATIM (verified: 926us total).
// Rounds 24/25 post-mortem: the "adaptive same-XCD L2 exchange" HANGS.
// Mechanism: plain stores are invisible at the LLC for unbounded time
// (per-XCD L2s are write-back, non-probed). A non-co-XCD reader's L2 keeps
// STALE CLEAN fast-lines from a previous bench iteration (memset's zeros
// never invalidate them); tags repeat across iterations (2..512), so the
// poll FALSE-MATCHES when want reaches the stale tag -> run-ahead ->
// slot overwritten with tag t+2 while a lagging sibling polls ==t ->
// infinite spin -> GPU hang. No reader-side fix exists (cannot invalidate a
// single remote-stale L2 line). L2-exchange direction closed (r13, r24/25).
// Session ledger of closed directions:
//  - interleave hiding: loses to barrier coupling / grid loss (r10, r12)
//  - register-fat fusion (>64 weights/thread): unallocatable (r16-r20)
//  - local chain: DPP sums + early distributed publish + tagged words +
//    wave-local matvec already minimize it (r9, r11, r15)
//  - phase1: fully absorbed as bf16-MFMA prologue -> LDS (r22, r23)
// Remaining cost = agent-scope LLC publish->detect round trip per step: the
// only coherent cross-WG channel. HBM 1.7%, VALU 28% -> coherence-latency
// floor, not a bandwidth/compute roofline.
// Design: single kernel. PROLOGUE: each WG computes its own 64-col slices
// A=H@W1, B2=H@W2 via bf16 MFMA into LDS (128KB dyn). LOOP (round-15):
// tagged 8B agent words (store IS the publication), waves 1..4 publish
// j=0..3 at step start / wave 0 publishes j=4 at tail, wave-0-only poll
// with self-j4 register substitute, DPP cross-lane sums, wave-local
// ds_read_b128 matvec, 2 barriers/step, grid 256.

#define BB 32
#define SS 512
#define DD 512
#define NS 5

#define EXCH_U64_PER_B 128                           // 2 slots x 64 (40 used)
#define EXCH_BYTES ((size_t)BB * EXCH_U64_PER_B * 8) // 32 KB
#define WS_NEED    EXCH_BYTES
#define DYN_LDS_BYTES ((size_t)2 * SS * 64 * 2)      // 128 KB (aS + bS)

typedef __attribute__((ext_vector_type(4))) float f32x4;
typedef __attribute__((ext_vector_type(8))) __bf16 bf16x8;

// ---- DPP cross-lane sum (rocPRIM sequence); ctrl words are template consts.
template <int CTRL, int RMASK, int BMASK, bool BC>
__device__ __forceinline__ float dpp_term(float x) {
  return __uint_as_float((unsigned)__builtin_amdgcn_update_dpp(
      0, (int)__float_as_uint(x), CTRL, RMASK, BMASK, BC));
}
__device__ __forceinline__ float wave_sum64(float x) {
  x += dpp_term<0xB1, 0xF, 0xF, true>(x);   // quad_perm [1,0,3,2] (xor 1)
  x += dpp_term<0x4E, 0xF, 0xF, true>(x);   // quad_perm [2,3,0,1] (xor 2)
  x += dpp_term<0x141, 0xF, 0xF, true>(x);  // row_half_mirror     (xor 4)
  x += dpp_term<0x140, 0xF, 0xF, true>(x);  // row_mirror          (xor 8)
  x += dpp_term<0x142, 0xA, 0xF, false>(x); // row_bcast15 -> rows 1,3
  x += dpp_term<0x143, 0xC, 0xF, false>(x); // row_bcast31 -> rows 2,3
  return x;                                 // lane 63: sum of all 64
}
__device__ __forceinline__ float group8_sum(float x) {
  x += dpp_term<0xB1, 0xF, 0xF, true>(x);
  x += dpp_term<0x4E, 0xF, 0xF, true>(x);
  x += dpp_term<0x141, 0xF, 0xF, true>(x);
  return x;
}

// grid 256 = 8 WGs/batch; bid = g*32+b.
__global__ void __launch_bounds__(512) th_fused(
    const float* __restrict__ H, const float* __restrict__ v,
    const float* __restrict__ W1, const float* __restrict__ W2,
    const float* __restrict__ W3,
    float* __restrict__ Ob,            // d_out: tilde rows only
    unsigned long long* __restrict__ exch) {
  const int tid = threadIdx.x;
  const int b = blockIdx.x & 31;
  const int g = blockIdx.x >> 5;     // 0..7: cols [g*64, g*64+64)
  const int q = tid >> 6;            // wave id == k-segment 0..7
  const int ln = tid & 63;
  const int col = (g << 6) + ln;

  __shared__ float tlds[DD];         // tilde_t row
  __shared__ float pm[DD];           // matvec k-segment partials
  __shared__ float wl[8];            // softmax weights broadcast
  extern __shared__ __align__(16) unsigned char dynls[];
  __bf16* aS = (__bf16*)dynls;               // [SS][64]: A slice (own cols)
  __bf16* bS = aS + (size_t)SS * 64;         // [SS][64]: B2 slice (own cols)

  const float* Hb = H + (size_t)b * SS * DD;
  float* Op = Ob + (size_t)b * SS * DD;
  unsigned long long* eb = exch + (size_t)b * EXCH_U64_PER_B;

  // ================= PROLOGUE: A/B2 slices via bf16 MFMA -> LDS ===========
  {
    const int lm = ln & 15;            // row-in-tile (A) / col-in-tile (B,D)
    const int lkb = (ln >> 4) << 3;    // k-offset base: 0,8,16,24
    const int lr4 = (ln >> 4) << 2;    // D-row base: 0,4,8,12
#pragma unroll 1
    for (int mat = 0; mat < 2; ++mat) {
      const float* Wm = mat ? W2 : W1;
      __bf16* Out = mat ? bS : aS;
      f32x4 acc[4][4];
#pragma unroll
      for (int x = 0; x < 4; ++x)
#pragma unroll
        for (int y = 0; y < 4; ++y)
          acc[x][y] = (f32x4){0.f, 0.f, 0.f, 0.f};
#pragma unroll 1
      for (int s = 0; s < 16; ++s) {
        const int kb = s * 32 + lkb;
        bf16x8 af[4];
#pragma unroll
        for (int mt = 0; mt < 4; ++mt) {
          const float* hp = Hb + (size_t)(q * 64 + mt * 16 + lm) * DD + kb;
          float4 u0 = *(const float4*)hp;
          float4 u1 = *(const float4*)(hp + 4);
          bf16x8 t;
          t[0] = (__bf16)u0.x; t[1] = (__bf16)u0.y;
          t[2] = (__bf16)u0.z; t[3] = (__bf16)u0.w;
          t[4] = (__bf16)u1.x; t[5] = (__bf16)u1.y;
          t[6] = (__bf16)u1.z; t[7] = (__bf16)u1.w;
          af[mt] = t;
        }
#pragma unroll
        for (int nt = 0; nt < 4; ++nt) {
          const float* wp = Wm + (size_t)kb * DD + (g * 64 + nt * 16 + lm);
          bf16x8 bfr;
#pragma unroll
          for (int i = 0; i < 8; ++i) bfr[i] = (__bf16)wp[(size_t)i * DD];
#pragma unroll
          for (int mt = 0; mt < 4; ++mt)
            acc[mt][nt] = __builtin_amdgcn_mfma_f32_16x16x32_bf16(
                af[mt], bfr, acc[mt][nt], 0, 0, 0);
        }
      }
#pragma unroll
      for (int mt = 0; mt < 4; ++mt)
#pragma unroll
        for (int nt = 0; nt < 4; ++nt)
#pragma unroll
          for (int i = 0; i < 4; ++i)
            Out[(size_t)(q * 64 + mt * 16 + lr4 + i) * 64 + nt * 16 + lm] =
                (__bf16)acc[mt][nt][i];
    }
    __syncthreads();                 // A/B2 slices visible WG-wide
  }

  // ================= recurrence (round-15 loop, A/B2 from LDS) ============
  // W3 slice in plain VGPRs: wa[i] = W3[q*64+i][col]
  float wa[64];
#pragma unroll
  for (int i = 0; i < 64; ++i)
    wa[i] = W3[(size_t)(q * 64 + i) * DD + col];

  // waves 0..4: replica rings over this WG's 64 cols (row s in slot s%5)
  float v_col = (q < NS) ? v[col] : 0.f;
  float aA[NS] = {0.f, 0.f, 0.f, 0.f, 0.f};
  float cC[NS] = {0.f, 0.f, 0.f, 0.f, 0.f};
  float tl[NS] = {0.f, 0.f, 0.f, 0.f, 0.f};
  float s4_prev = 0.f;               // wave 0: own j=4 score (all lanes)
  float h_cur = Hb[tid];
  float btB = (q < NS) ? (float)bS[64 + ln] : 0.f;  // B2 row 1 (own col)

  if (tid < NS) wl[tid] = 0.2f;      // step-0 weights: exactly uniform

#pragma unroll 1
  for (int t5 = 0; t5 < 515; t5 += 5) {
#pragma unroll
    for (int p = 0; p < NS; ++p) {
      const int t = t5 + p;
      if (t < SS) {
        const bool pub = (t + 1 < SS);

        // ---- prefetches (A row t, B2 row t+2 from LDS; H row t+1 global)
        float aN_v = 0.f, bt2 = 0.f;
        if (q < NS) {
          aN_v = (float)aS[(size_t)t * 64 + ln];
          if (t + 2 < SS) bt2 = (float)bS[(size_t)(t + 2) * 64 + ln];
        }
        float h_nxt = 0.f;
        if (pub) h_nxt = Hb[(size_t)(t + 1) * DD + tid];

        // ---- waves 1..4: EARLY publish of score j=q-1 for step t+1
        if (q >= 1 && q < NS && pub) {
          float aa = aA[(p + 1) % NS];
          aa = (q == 2) ? aA[(p + 2) % NS] : aa;
          aa = (q == 3) ? aA[(p + 3) % NS] : aa;
          aa = (q == 4) ? aA[(p + 4) % NS] : aa;
          float cc = cC[(p + 1) % NS];
          cc = (q == 2) ? cC[(p + 2) % NS] : cc;
          cc = (q == 3) ? cC[(p + 3) % NS] : cc;
          cc = (q == 4) ? cC[(p + 4) % NS] : cc;
          float x = aa + btB + cc;
          float e = __expf(2.0f * x);
          float s = (1.0f - 2.0f / (e + 1.0f)) * v_col;
          s = wave_sum64(s);                       // lane 63 = total
          if (ln == 63)
            __hip_atomic_store(&eb[(size_t)((t + 1) & 1) * 64 + (q - 1) * 8 + g],
                (unsigned long long)__float_as_uint(s) |
                    ((unsigned long long)(t + 2) << 32),
                __ATOMIC_RELAXED, __HIP_MEMORY_SCOPE_AGENT);
        }

        // ---- wave 0: poll tagged words (slot t&1, tag t+1) -> softmax -> wl
        if (q == 0 && t >= 1) {
          const unsigned long long* wsl = eb + (size_t)(t & 1) * 64;
          float pv = 0.f;
          if (ln < 40) {
            if (!((ln >> 3) == 4 && (ln & 7) == g)) {
              unsigned long long w;
              do {
                w = __hip_atomic_load(&wsl[ln], __ATOMIC_RELAXED,
                                      __HIP_MEMORY_SCOPE_AGENT);
              } while ((unsigned)(w >> 32) != (unsigned)(t + 1));
              pv = __uint_as_float((unsigned)w);
            } else {
              pv = s4_prev;
            }
          }
          pv = group8_sum(pv);             // each 8-group holds its j-total
          float sc0 = __shfl(pv, 0, 64);
          float sc1 = __shfl(pv, 8, 64);
          float sc2 = __shfl(pv, 16, 64);
          float sc3 = __shfl(pv, 24, 64);
          float sc4 = __shfl(pv, 32, 64);
          float mx = fmaxf(fmaxf(fmaxf(sc0, sc1), fmaxf(sc2, sc3)), sc4);
          float e0 = __expf(sc0 - mx), e1 = __expf(sc1 - mx);
          float e2 = __expf(sc2 - mx), e3 = __expf(sc3 - mx);
          float e4 = __expf(sc4 - mx);
          float inv = 1.0f / (e0 + e1 + e2 + e3 + e4);
          float wv = e0 * inv;
          wv = (ln == 1) ? e1 * inv : wv;
          wv = (ln == 2) ? e2 * inv : wv;
          wv = (ln == 3) ? e3 * inv : wv;
          wv = (ln == 4) ? e4 * inv : wv;
          if (ln < NS) wl[ln] = wv;
        }
        __syncthreads();                           // A: weights ready

        // ---- all threads: tilde row (registers + 5 broadcast LDS reads)
        float w0 = wl[0], w1 = wl[1], w2 = wl[2], w3_ = wl[3], w4 = wl[4];
        float hh = w0 * tl[p];
        hh = fmaf(w1, tl[(p + 1) % NS], hh);
        hh = fmaf(w2, tl[(p + 2) % NS], hh);
        hh = fmaf(w3_, tl[(p + 3) % NS], hh);
        hh = fmaf(w4, tl[(p + 4) % NS], hh);
        float tld = h_cur + fmaxf(hh, 0.f);
        tl[p] = tld;
        tlds[tid] = tld;
        if (g == 0) Op[(size_t)t * DD + tid] = tld;  // output row t (no reader)
        // wave-local: matvec reads ONLY this wave's own tlds segment
        asm volatile("s_waitcnt lgkmcnt(0)" ::: "memory");

        // ---- matvec: own 64 cols, k in [q*64, q*64+64), wave-uniform reads
        float a0 = 0.f, a1 = 0.f, a2 = 0.f, a3 = 0.f;
        const f32x4* tv = (const f32x4*)&tlds[q << 6];
#pragma unroll
        for (int i = 0; i < 16; ++i) {
          f32x4 t4 = tv[i];
          a0 = fmaf(t4.x, wa[4 * i + 0], a0);
          a1 = fmaf(t4.y, wa[4 * i + 1], a1);
          a2 = fmaf(t4.z, wa[4 * i + 2], a2);
          a3 = fmaf(t4.w, wa[4 * i + 3], a3);
        }
        pm[tid] = (a0 + a1) + (a2 + a3);
        __syncthreads();                           // C: pm ready

        // ---- waves 0..4: k-reduce + ring update; wave 0: score j=4, publish
        if (q < NS) {
          float c = 0.f;
#pragma unroll
          for (int s = 0; s < 8; ++s) c += pm[s * 64 + ln];
          aA[p] = aN_v;                            // A row t -> slot t%5
          cC[p] = c;                               // c row t -> slot t%5
          if (q == 0 && pub) {
            float x = aN_v + btB + c;              // row t, bt = row t+1
            float e = __expf(2.0f * x);
            float s4 = (1.0f - 2.0f / (e + 1.0f)) * v_col;
            s4 = wave_sum64(s4);                   // lane 63 = total
            if (ln == 63)
              __hip_atomic_store(&eb[(size_t)((t + 1) & 1) * 64 + 32 + g],
                  (unsigned long long)__float_as_uint(s4) |
                      ((unsigned long long)(t + 2) << 32),
                  __ATOMIC_RELAXED, __HIP_MEMORY_SCOPE_AGENT);
            s4_prev = __shfl(s4, 63, 64);          // off-critical broadcast
          }
          btB = bt2;
        }
        h_cur = h_nxt;
      }
    }
  }
}

extern "C" void kernel_launch(void* const* d_in, const int* in_sizes, int n_in,
                              void* d_out, int out_size, void* d_ws, size_t ws_size,
                              hipStream_t stream) {
  const float* H  = (const float*)d_in[0];
  const float* v  = (const float*)d_in[1];
  const float* W1 = (const float*)d_in[2];
  const float* W2 = (const float*)d_in[3];
  const float* W3 = (const float*)d_in[4];
  float* out = (float*)d_out;

  if (ws_size < WS_NEED) return;

  unsigned long long* exch = (unsigned long long*)d_ws;

  (void)hipMemsetAsync(exch, 0, EXCH_BYTES, stream);
  hipLaunchKernelGGL(th_fused, dim3(BB * 8), dim3(512), DYN_LDS_BYTES, stream,
                     H, v, W1, W2, W3, out, exch);
}